// Round 1
// baseline (656.317 us; speedup 1.0000x reference)
//
#include <hip/hip_runtime.h>

// NeRF MLP fully fused: x[N,48] -> (pts[:,:32] -> s0 relu -> s1 relu -> s2) ;
// sigma = s2[:,0], geo = s2[:,1:16]; concat(views[:,32:48], geo) -> c0 relu
// -> c1 relu -> c2 relu -> c3 ; out[N,4] = {color3, sigma}
//
// Strategy: per-wave independent 16-row tiles, f16 MFMA 16x16x32, all weight
// B-fragments resident in VGPRs (loaded once per block), LDS only for the
// C/D->A layout round-trip. No __syncthreads in the main loop.

typedef _Float16 half8  __attribute__((ext_vector_type(8)));
typedef _Float16 half4v __attribute__((ext_vector_type(4)));
typedef float    floatx4 __attribute__((ext_vector_type(4)));

#define NPTS   2097152
#define NTILES (NPTS / 64)   // 64 rows per block-iteration (4 waves x 16)
#define XS     72            // padded LDS row stride in halfs (144B = 9*16B)

__device__ __forceinline__ half8 load_bfrag(const float* __restrict__ W,
                                            int Kr, int Nr, int n, int kbase) {
    // B[k][n] fragment: lane holds n = (given), k = kbase..kbase+7
    half8 f;
#pragma unroll
    for (int j = 0; j < 8; ++j) {
        int k = kbase + j;
        float v = (k < Kr && n < Nr) ? W[k * Nr + n] : 0.0f;
        f[j] = (_Float16)v;
    }
    return f;
}

__global__ __launch_bounds__(256, 2)
void nerf_fused(const float* __restrict__ x,
                const float* __restrict__ ws0, const float* __restrict__ ws1,
                const float* __restrict__ ws2, const float* __restrict__ wc0,
                const float* __restrict__ wc1, const float* __restrict__ wc2,
                const float* __restrict__ wc3, float* __restrict__ out) {
    // per-wave buffers (indexed by wave id -> no cross-wave sharing, no barriers)
    __shared__ __align__(16) _Float16 sX[4][16][XS]; // cols 0..31 pts, 32..47 views, 48..62 geo, 63 zero
    __shared__ __align__(16) _Float16 sH[4][16][XS]; // activation ping buffer
    __shared__ __align__(16) float    sO[4][16][4];  // output assembly {c0,c1,c2,sigma}

    const int tid  = threadIdx.x;
    const int w    = tid >> 6;
    const int lane = tid & 63;
    const int l16  = lane & 15;
    const int quad = lane >> 4;

    // ---- weight B-fragments -> registers (once per block, ~70KB L2-cached) ----
    half8 Bs0[4], Bc0[4], Bs2[2], Bc3[2];
    half8 Bs1[4][2], Bc1[4][2], Bc2[4][2];
#pragma unroll
    for (int nt = 0; nt < 4; ++nt) {
        Bs0[nt] = load_bfrag(ws0, 32, 64, nt*16 + l16, quad*8);
        Bc0[nt] = load_bfrag(wc0, 31, 64, nt*16 + l16, quad*8);  // k=31 pad -> 0
#pragma unroll
        for (int ks = 0; ks < 2; ++ks) {
            Bs1[nt][ks] = load_bfrag(ws1, 64, 64, nt*16 + l16, ks*32 + quad*8);
            Bc1[nt][ks] = load_bfrag(wc1, 64, 64, nt*16 + l16, ks*32 + quad*8);
            Bc2[nt][ks] = load_bfrag(wc2, 64, 64, nt*16 + l16, ks*32 + quad*8);
        }
    }
#pragma unroll
    for (int ks = 0; ks < 2; ++ks) {
        Bs2[ks] = load_bfrag(ws2, 64, 16, l16, ks*32 + quad*8);
        Bc3[ks] = load_bfrag(wc3, 64,  3, l16, ks*32 + quad*8);  // n>=3 pad -> 0
    }

    if (lane < 16) sX[w][lane][63] = (_Float16)0.0f;  // c0 K-pad column, persists

    const floatx4 vzero = {0.f, 0.f, 0.f, 0.f};

    // loop-invariant staging map: 16 rows x 12 float4 = 192 float4, 3 per lane
    int srow[3], scol[3];
#pragma unroll
    for (int p = 0; p < 3; ++p) {
        int t = lane + 64*p;
        srow[p] = t / 12;
        scol[p] = (t % 12) * 4;
    }

    int tile = blockIdx.x;
    float4 xv0, xv1, xv2;
    {
        const float4* xb = (const float4*)(x + (size_t)(tile*64 + w*16) * 48);
        xv0 = xb[lane]; xv1 = xb[lane + 64]; xv2 = xb[lane + 128];
    }

    while (tile < NTILES) {
        // ---- prefetch next tile's x (overlaps whole pipeline below) ----
        int next = tile + gridDim.x;
        int pf = next < NTILES ? next : tile;
        const float4* xb = (const float4*)(x + (size_t)(pf*64 + w*16) * 48);
        float4 nv0 = xb[lane], nv1 = xb[lane + 64], nv2 = xb[lane + 128];

        // ---- stage current x into sX as f16 ----
        float4 vv[3] = {xv0, xv1, xv2};
#pragma unroll
        for (int p = 0; p < 3; ++p) {
            half4v h;
            h[0] = (_Float16)vv[p].x; h[1] = (_Float16)vv[p].y;
            h[2] = (_Float16)vv[p].z; h[3] = (_Float16)vv[p].w;
            *(half4v*)&sX[w][srow[p]][scol[p]] = h;
        }

        floatx4 acc[4];

        // ---- s0: h = relu(pts @ s0), K=32 ----
        half8 a0 = *(const half8*)&sX[w][l16][quad*8];
#pragma unroll
        for (int nt = 0; nt < 4; ++nt)
            acc[nt] = __builtin_amdgcn_mfma_f32_16x16x32_f16(a0, Bs0[nt], vzero, 0, 0, 0);
#pragma unroll
        for (int nt = 0; nt < 4; ++nt)
#pragma unroll
            for (int i = 0; i < 4; ++i)
                sH[w][quad*4 + i][nt*16 + l16] = (_Float16)fmaxf(acc[nt][i], 0.f);

        // ---- s1: h = relu(h @ s1), K=64 ----
        half8 a1 = *(const half8*)&sH[w][l16][quad*8];
        half8 a2 = *(const half8*)&sH[w][l16][32 + quad*8];
#pragma unroll
        for (int nt = 0; nt < 4; ++nt) {
            acc[nt] = __builtin_amdgcn_mfma_f32_16x16x32_f16(a1, Bs1[nt][0], vzero,  0, 0, 0);
            acc[nt] = __builtin_amdgcn_mfma_f32_16x16x32_f16(a2, Bs1[nt][1], acc[nt], 0, 0, 0);
        }
#pragma unroll
        for (int nt = 0; nt < 4; ++nt)
#pragma unroll
            for (int i = 0; i < 4; ++i)
                sH[w][quad*4 + i][nt*16 + l16] = (_Float16)fmaxf(acc[nt][i], 0.f);

        // ---- s2: 16 outputs, NO relu. col0 = sigma, cols1..15 = geo ----
        a1 = *(const half8*)&sH[w][l16][quad*8];
        a2 = *(const half8*)&sH[w][l16][32 + quad*8];
        floatx4 accS = __builtin_amdgcn_mfma_f32_16x16x32_f16(a1, Bs2[0], vzero, 0, 0, 0);
        accS         = __builtin_amdgcn_mfma_f32_16x16x32_f16(a2, Bs2[1], accS,  0, 0, 0);
#pragma unroll
        for (int i = 0; i < 4; ++i) {
            int row = quad*4 + i;
            if (l16 == 0) sO[w][row][3] = accS[i];                      // sigma (f32)
            else          sX[w][row][47 + l16] = (_Float16)accS[i];     // geo -> cols 48..62
        }

        // ---- c0: h = relu(concat(views,geo) @ c0), K=32 from sX cols 32..63 ----
        half8 a3 = *(const half8*)&sX[w][l16][32 + quad*8];
#pragma unroll
        for (int nt = 0; nt < 4; ++nt)
            acc[nt] = __builtin_amdgcn_mfma_f32_16x16x32_f16(a3, Bc0[nt], vzero, 0, 0, 0);
#pragma unroll
        for (int nt = 0; nt < 4; ++nt)
#pragma unroll
            for (int i = 0; i < 4; ++i)
                sH[w][quad*4 + i][nt*16 + l16] = (_Float16)fmaxf(acc[nt][i], 0.f);

        // ---- c1 ----
        a1 = *(const half8*)&sH[w][l16][quad*8];
        a2 = *(const half8*)&sH[w][l16][32 + quad*8];
#pragma unroll
        for (int nt = 0; nt < 4; ++nt) {
            acc[nt] = __builtin_amdgcn_mfma_f32_16x16x32_f16(a1, Bc1[nt][0], vzero,  0, 0, 0);
            acc[nt] = __builtin_amdgcn_mfma_f32_16x16x32_f16(a2, Bc1[nt][1], acc[nt], 0, 0, 0);
        }
#pragma unroll
        for (int nt = 0; nt < 4; ++nt)
#pragma unroll
            for (int i = 0; i < 4; ++i)
                sH[w][quad*4 + i][nt*16 + l16] = (_Float16)fmaxf(acc[nt][i], 0.f);

        // ---- c2 ----
        a1 = *(const half8*)&sH[w][l16][quad*8];
        a2 = *(const half8*)&sH[w][l16][32 + quad*8];
#pragma unroll
        for (int nt = 0; nt < 4; ++nt) {
            acc[nt] = __builtin_amdgcn_mfma_f32_16x16x32_f16(a1, Bc2[nt][0], vzero,  0, 0, 0);
            acc[nt] = __builtin_amdgcn_mfma_f32_16x16x32_f16(a2, Bc2[nt][1], acc[nt], 0, 0, 0);
        }
#pragma unroll
        for (int nt = 0; nt < 4; ++nt)
#pragma unroll
            for (int i = 0; i < 4; ++i)
                sH[w][quad*4 + i][nt*16 + l16] = (_Float16)fmaxf(acc[nt][i], 0.f);

        // ---- c3: 3 real outputs, NO relu ----
        a1 = *(const half8*)&sH[w][l16][quad*8];
        a2 = *(const half8*)&sH[w][l16][32 + quad*8];
        floatx4 accC = __builtin_amdgcn_mfma_f32_16x16x32_f16(a1, Bc3[0], vzero, 0, 0, 0);
        accC         = __builtin_amdgcn_mfma_f32_16x16x32_f16(a2, Bc3[1], accC,  0, 0, 0);
        if (l16 < 3) {
#pragma unroll
            for (int i = 0; i < 4; ++i)
                sO[w][quad*4 + i][l16] = accC[i];
        }

        // ---- write out[row] = {color3, sigma} as float4 ----
        if (lane < 16) {
            float4 o = *(const float4*)&sO[w][lane][0];
            ((float4*)out)[(size_t)tile*64 + w*16 + lane] = o;
        }

        xv0 = nv0; xv1 = nv1; xv2 = nv2;
        tile = next;
    }
}

extern "C" void kernel_launch(void* const* d_in, const int* in_sizes, int n_in,
                              void* d_out, int out_size, void* d_ws, size_t ws_size,
                              hipStream_t stream) {
    nerf_fused<<<1024, 256, 0, stream>>>(
        (const float*)d_in[0], (const float*)d_in[1], (const float*)d_in[2],
        (const float*)d_in[3], (const float*)d_in[4], (const float*)d_in[5],
        (const float*)d_in[6], (const float*)d_in[7], (float*)d_out);
}

// Round 2
// 549.320 us; speedup vs baseline: 1.1948x; 1.1948x over previous
//
#include <hip/hip_runtime.h>

// NeRF MLP, fully register-resident chain.
// Transposed MFMA formulation: D = A(W^T) * B(act^T), 16x16x32 f16.
//   A-frag: m=lane&15 (out feat), k=quad*8+j  (weights, pre-packed)
//   B-frag: n=lane&15 (point),   k=quad*8+j  (activations)
//   D     : col=lane&15 (point), row=quad*4+i (out feat)
// Feature ordering of every hidden layer is chosen so that D's registers,
// relu'd+converted, ARE the next layer's B-fragment (per-lane pack, no
// cross-lane movement). Hidden-layer feature at B slot (c,q,j) is the
// previous D's acc[2c + (j>>2)][j&3]  => logical feat phi = (2c+(j>>2))*16
// + q*4 + (j&3); weight packs below apply this permutation on both sides.
// Zero LDS; x loads land directly in B-slot order.

typedef _Float16 half8  __attribute__((ext_vector_type(8)));
typedef float    floatx4 __attribute__((ext_vector_type(4)));

#define NPTS   2097152
#define NTILES (NPTS / 64)   // 4 waves/block, 16 pts per wave per tile

// ---------- weight pre-pack: 36 fragments x 64 lanes x 8 halfs -> d_ws ----
__global__ void prep_weights(const float* __restrict__ ws0, const float* __restrict__ ws1,
                             const float* __restrict__ ws2, const float* __restrict__ wc0,
                             const float* __restrict__ wc1, const float* __restrict__ wc2,
                             const float* __restrict__ wc3, _Float16* __restrict__ wpack) {
    int t = blockIdx.x * blockDim.x + threadIdx.x;
    if (t >= 36 * 64) return;
    int fid = t >> 6, lane = t & 63, l16 = lane & 15, q = lane >> 4;
#pragma unroll
    for (int j = 0; j < 8; ++j) {
        int phi = (2 * 0 + (j >> 2)) * 16 + q * 4 + (j & 3); // c merged below
        float v = 0.f;
        if (fid < 4) {                       // s0: natural input dims, mt=fid
            v = ws0[(q * 8 + j) * 64 + fid * 16 + l16];
        } else if (fid < 12) {               // s1: mt=(fid-4)>>1, c=(fid-4)&1
            int mt = (fid - 4) >> 1, c = (fid - 4) & 1;
            int p = (2 * c + (j >> 2)) * 16 + q * 4 + (j & 3);
            v = ws1[p * 64 + mt * 16 + l16];
        } else if (fid < 14) {               // s2: c=fid-12, 16 outs
            int c = fid - 12;
            int p = (2 * c + (j >> 2)) * 16 + q * 4 + (j & 3);
            v = ws2[p * 16 + l16];
        } else if (fid < 18) {               // c0: mt=fid-14; views j<4, geo j>=4
            int mt = fid - 14;
            if (j < 4) v = wc0[(q * 4 + j) * 64 + mt * 16 + l16];
            else {
                int g = q * 4 + (j - 4);     // geo feat index (0 => sigma slot, pad)
                v = (g == 0) ? 0.f : wc0[(15 + g) * 64 + mt * 16 + l16];
            }
        } else if (fid < 26) {               // c1
            int mt = (fid - 18) >> 1, c = (fid - 18) & 1;
            int p = (2 * c + (j >> 2)) * 16 + q * 4 + (j & 3);
            v = wc1[p * 64 + mt * 16 + l16];
        } else if (fid < 34) {               // c2
            int mt = (fid - 26) >> 1, c = (fid - 26) & 1;
            int p = (2 * c + (j >> 2)) * 16 + q * 4 + (j & 3);
            v = wc2[p * 64 + mt * 16 + l16];
        } else {                             // c3: c=fid-34, 3 outs (pad rows >=3)
            int c = fid - 34;
            int p = (2 * c + (j >> 2)) * 16 + q * 4 + (j & 3);
            v = (l16 < 3) ? wc3[p * 3 + l16] : 0.f;
        }
        (void)phi;
        wpack[t * 8 + j] = (_Float16)v;
    }
}

__device__ __forceinline__ half8 packrelu(floatx4 a, floatx4 b) {
    half8 r;
    r[0] = (_Float16)fmaxf(a[0], 0.f); r[1] = (_Float16)fmaxf(a[1], 0.f);
    r[2] = (_Float16)fmaxf(a[2], 0.f); r[3] = (_Float16)fmaxf(a[3], 0.f);
    r[4] = (_Float16)fmaxf(b[0], 0.f); r[5] = (_Float16)fmaxf(b[1], 0.f);
    r[6] = (_Float16)fmaxf(b[2], 0.f); r[7] = (_Float16)fmaxf(b[3], 0.f);
    return r;
}

__global__ __launch_bounds__(256, 2)
void nerf_fused(const float* __restrict__ x, const _Float16* __restrict__ wpack,
                float* __restrict__ out) {
    const int lane = threadIdx.x & 63;
    const int w    = threadIdx.x >> 6;
    const int l16  = lane & 15;
    const int q    = lane >> 4;

    // 36 weight A-fragments -> registers (coalesced b128 loads)
    half8 W[36];
    const half8* wp = (const half8*)wpack;
#pragma unroll
    for (int f = 0; f < 36; ++f) W[f] = wp[f * 64 + lane];

    const floatx4 vz = {0.f, 0.f, 0.f, 0.f};
    const float4* xb = (const float4*)x;

    int tile = blockIdx.x;
    float4 vA, vB, vC;
    {
        size_t base = (size_t)(tile * 64 + w * 16 + l16) * 12;
        vA = xb[base + q * 2]; vB = xb[base + q * 2 + 1]; vC = xb[base + 8 + q];
    }

    while (tile < NTILES) {
        int next = tile + gridDim.x;
        int pf = next < NTILES ? next : tile;
        size_t nbase = (size_t)(pf * 64 + w * 16 + l16) * 12;
        float4 nA = xb[nbase + q * 2], nB = xb[nbase + q * 2 + 1], nC = xb[nbase + 8 + q];

        // ---- s0: B directly from x (dims q*8..q*8+7), K=32 ----
        half8 b0, b1;
        b0[0] = (_Float16)vA.x; b0[1] = (_Float16)vA.y; b0[2] = (_Float16)vA.z; b0[3] = (_Float16)vA.w;
        b0[4] = (_Float16)vB.x; b0[5] = (_Float16)vB.y; b0[6] = (_Float16)vB.z; b0[7] = (_Float16)vB.w;
        floatx4 acc[4], a2[4];
#pragma unroll
        for (int mt = 0; mt < 4; ++mt)
            acc[mt] = __builtin_amdgcn_mfma_f32_16x16x32_f16(W[mt], b0, vz, 0, 0, 0);

        // ---- s1 ----
        b0 = packrelu(acc[0], acc[1]); b1 = packrelu(acc[2], acc[3]);
#pragma unroll
        for (int mt = 0; mt < 4; ++mt) {
            a2[mt] = __builtin_amdgcn_mfma_f32_16x16x32_f16(W[4 + mt * 2], b0, vz,     0, 0, 0);
            a2[mt] = __builtin_amdgcn_mfma_f32_16x16x32_f16(W[5 + mt * 2], b1, a2[mt], 0, 0, 0);
        }

        // ---- s2 (no relu): sigma = feat0, geo = feats 1..15 ----
        b0 = packrelu(a2[0], a2[1]); b1 = packrelu(a2[2], a2[3]);
        floatx4 accS;
        accS = __builtin_amdgcn_mfma_f32_16x16x32_f16(W[12], b0, vz,   0, 0, 0);
        accS = __builtin_amdgcn_mfma_f32_16x16x32_f16(W[13], b1, accS, 0, 0, 0);
        float sigma = accS[0];   // valid in quad 0 lanes (pt = l16)

        // ---- c0: B = {views q*4..q*4+3 from vC, geo from accS}, K=32 ----
        half8 bc;
        bc[0] = (_Float16)vC.x; bc[1] = (_Float16)vC.y; bc[2] = (_Float16)vC.z; bc[3] = (_Float16)vC.w;
        bc[4] = (q == 0) ? (_Float16)0.f : (_Float16)accS[0];
        bc[5] = (_Float16)accS[1]; bc[6] = (_Float16)accS[2]; bc[7] = (_Float16)accS[3];
#pragma unroll
        for (int mt = 0; mt < 4; ++mt)
            acc[mt] = __builtin_amdgcn_mfma_f32_16x16x32_f16(W[14 + mt], bc, vz, 0, 0, 0);

        // ---- c1 ----
        b0 = packrelu(acc[0], acc[1]); b1 = packrelu(acc[2], acc[3]);
#pragma unroll
        for (int mt = 0; mt < 4; ++mt) {
            a2[mt] = __builtin_amdgcn_mfma_f32_16x16x32_f16(W[18 + mt * 2], b0, vz,     0, 0, 0);
            a2[mt] = __builtin_amdgcn_mfma_f32_16x16x32_f16(W[19 + mt * 2], b1, a2[mt], 0, 0, 0);
        }

        // ---- c2 ----
        b0 = packrelu(a2[0], a2[1]); b1 = packrelu(a2[2], a2[3]);
#pragma unroll
        for (int mt = 0; mt < 4; ++mt) {
            acc[mt] = __builtin_amdgcn_mfma_f32_16x16x32_f16(W[26 + mt * 2], b0, vz,      0, 0, 0);
            acc[mt] = __builtin_amdgcn_mfma_f32_16x16x32_f16(W[27 + mt * 2], b1, acc[mt], 0, 0, 0);
        }

        // ---- c3 (no relu, 3 outs) ----
        b0 = packrelu(acc[0], acc[1]); b1 = packrelu(acc[2], acc[3]);
        floatx4 accC;
        accC = __builtin_amdgcn_mfma_f32_16x16x32_f16(W[34], b0, vz,   0, 0, 0);
        accC = __builtin_amdgcn_mfma_f32_16x16x32_f16(W[35], b1, accC, 0, 0, 0);

        // ---- store: quad-0 lanes hold color rows 0..2 + sigma for pt=l16 ----
        if (lane < 16) {
            float4 o;
            o.x = accC[0]; o.y = accC[1]; o.z = accC[2]; o.w = sigma;
            ((float4*)out)[(size_t)tile * 64 + w * 16 + lane] = o;
        }

        vA = nA; vB = nB; vC = nC;
        tile = next;
    }
}

extern "C" void kernel_launch(void* const* d_in, const int* in_sizes, int n_in,
                              void* d_out, int out_size, void* d_ws, size_t ws_size,
                              hipStream_t stream) {
    _Float16* wpack = (_Float16*)d_ws;  // 36*64*8 halfs = 36 KB
    prep_weights<<<9, 256, 0, stream>>>(
        (const float*)d_in[1], (const float*)d_in[2], (const float*)d_in[3],
        (const float*)d_in[4], (const float*)d_in[5], (const float*)d_in[6],
        (const float*)d_in[7], wpack);
    nerf_fused<<<1024, 256, 0, stream>>>((const float*)d_in[0], wpack, (float*)d_out);
}